// Round 4
// baseline (37.932 us; speedup 1.0000x reference)
//
#include <hip/hip_runtime.h>

// YOLOv4 head transform, B=16, A=3, nc=80, H=W=76.
// x[b, a*85+ch, h, w] -> out[b, a*H*W + h*W + w, k], k in 0..83.
// R11: R10's intra-block pipeline, FIXED. R10's VGPR=32 proved hipcc sank
// the prefetch loads to their use, deleting the pipeline. Changes:
//  (1) sched_barrier(0) right after the prefetch issue pins loads above the
//      drain (issue-early / wait-late survives).
//  (2) branchless staging (idx clamped to NQ-1; duplicate lanes load+write
//      identical values to the same LDS slot - benign) so no divergent
//      control flow surrounds the loads.
//  (3) NROWS=2 -> grid 48*38=1824 blocks (R8-level TLP) while tile 1's
//      loads hide under tile 0's drain.
// LDS 85*77*4=26.2KB single-buffered, two register sets rA/rB.

#define YHW 5776
#define W76 76
#define NROWS 2             // rows (tiles) per block
#define NRB 38              // row-groups per plane = 76/2
#define LSTRIDE 77
#define NTHREADS 512
#define QN 19               // float4s per channel row (76 floats)
#define NQ (85 * QN)        // 1615
#define NJ 4                // ceil(1615/512)

typedef float f4v __attribute__((ext_vector_type(4)));

__device__ __forceinline__ float fsigmoid(float v) {
    return __builtin_amdgcn_rcpf(1.0f + __expf(-v));
}

// Branchless: clamped lanes duplicate the idx=NQ-1 load (same cache line,
// broadcast). toff is compile-time per call site.
__device__ __forceinline__ void issue_loads(const float* __restrict__ src, int toff,
                                            f4v r[NJ], int tid) {
    #pragma unroll
    for (int j = 0; j < NJ; ++j) {
        int idx = tid + NTHREADS * j;
        idx = (idx < NQ) ? idx : (NQ - 1);
        const int ch = idx / QN;
        const int q  = idx - ch * QN;
        r[j] = *reinterpret_cast<const f4v*>(src + (size_t)ch * YHW + 4 * q + toff);
    }
}

__device__ __forceinline__ void transform(const f4v r[NJ], float (*lds)[LSTRIDE], int tid) {
    #pragma unroll
    for (int j = 0; j < NJ; ++j) {
        int idx = tid + NTHREADS * j;
        idx = (idx < NQ) ? idx : (NQ - 1);   // clamped lanes rewrite same value
        const int ch = idx / QN;
        const int q  = idx - ch * QN;
        f4v v = r[j];
        int row;
        if (ch < 2) {                   // tx,ty -> sigmoid*1.2-0.1
            v.x = fsigmoid(v.x) * 1.2f - 0.1f;
            v.y = fsigmoid(v.y) * 1.2f - 0.1f;
            v.z = fsigmoid(v.z) * 1.2f - 0.1f;
            v.w = fsigmoid(v.w) * 1.2f - 0.1f;
            row = ch;
        } else if (ch < 4) {            // tw,th -> exp
            v.x = __expf(v.x); v.y = __expf(v.y);
            v.z = __expf(v.z); v.w = __expf(v.w);
            row = ch;
        } else {                        // det + classes -> sigmoid
            v.x = fsigmoid(v.x); v.y = fsigmoid(v.y);
            v.z = fsigmoid(v.z); v.w = fsigmoid(v.w);
            row = (ch == 4) ? 84 : ch - 1;   // class ch -> row k (4..83)
        }
        const int p4 = 4 * q;
        lds[row][p4 + 0] = v.x;
        lds[row][p4 + 1] = v.y;
        lds[row][p4 + 2] = v.z;
        lds[row][p4 + 3] = v.w;
    }
}

__device__ __forceinline__ void drain(const float (*lds)[LSTRIDE], float* __restrict__ dst,
                                      int h, float ax, float ay, int tid) {
    const float inv = 1.0f / 76.0f;
    constexpr int total = W76 * 21;          // 1596
    #pragma unroll
    for (int u0 = 0; u0 < total; u0 += NTHREADS) {
        const int u = u0 + tid;
        if (u < total) {
            const int pp = u / 21;           // w coordinate directly
            const int c  = u - 21 * pp;
            f4v o;
            if (c == 0) {                    // box: rows 0..3, pure arithmetic
                const float sx = lds[0][pp];
                const float sy = lds[1][pp];
                const float ew = lds[2][pp];
                const float eh = lds[3][pp];
                const float bxc = (sx + (float)pp) * inv;
                const float byc = (sy + (float)h) * inv;
                const float bw  = ew * ax * inv;
                const float bh  = eh * ay * inv;
                const float bx1 = bxc - 0.5f * bw;
                const float by1 = byc - 0.5f * bh;
                o.x = bx1; o.y = by1; o.z = bx1 + bw; o.w = by1 + bh;
            } else {                         // classes k=4c..4c+3 at rows 4c..4c+3
                const float det = lds[84][pp];
                o.x = lds[4 * c + 0][pp] * det;
                o.y = lds[4 * c + 1][pp] * det;
                o.z = lds[4 * c + 2][pp] * det;
                o.w = lds[4 * c + 3][pp] * det;
            }
            *reinterpret_cast<f4v*>(dst + (size_t)pp * 84 + 4 * c) = o;
        }
    }
}

__global__ __launch_bounds__(NTHREADS) void yolo_kernel(const float* __restrict__ x,
                                                        float* __restrict__ out) {
    const int blk  = blockIdx.x;
    const int rb   = blk % NRB;
    const int ba   = blk / NRB;             // b*3 + a
    const int a    = ba % 3;
    const int row0 = rb * NROWS;

    __shared__ float lds[85][LSTRIDE];      // 26,180 B

    const int tid = threadIdx.x;
    const float* __restrict__ srcbase = x + (size_t)ba * 85 * YHW + (size_t)row0 * W76;
    float* __restrict__ dstbase = out + ((size_t)ba * YHW + (size_t)row0 * W76) * 84;

    const float ax = (a == 0) ? 1.5f : ((a == 1) ? 2.375f : 5.0f);
    const float ay = (a == 0) ? 2.0f : ((a == 1) ? 4.5f : 3.5f);

    f4v rA[NJ], rB[NJ];
    issue_loads(srcbase, 0, rA, tid);

    // ---- tile 0 ----
    transform(rA, lds, tid);
    __syncthreads();
    issue_loads(srcbase, W76, rB, tid);      // prefetch tile 1
    __builtin_amdgcn_sched_barrier(0);       // PIN: loads may not sink below
    drain(lds, dstbase, row0, ax, ay, tid);
    __syncthreads();

    // ---- tile 1 ----
    transform(rB, lds, tid);
    __syncthreads();
    drain(lds, dstbase + (size_t)W76 * 84, row0 + 1, ax, ay, tid);
}

extern "C" void kernel_launch(void* const* d_in, const int* in_sizes, int n_in,
                              void* d_out, int out_size, void* d_ws, size_t ws_size,
                              hipStream_t stream) {
    const float* x = (const float*)d_in[0];
    float* out = (float*)d_out;
    const int nblocks = 48 * NRB;           // 16*3*38 = 1824
    yolo_kernel<<<nblocks, NTHREADS, 0, stream>>>(x, out);
}

// Round 5
// 36.605 us; speedup vs baseline: 1.0363x; 1.0363x over previous
//
#include <hip/hip_runtime.h>

// YOLOv4 head transform, B=16, A=3, nc=80, H=W=76.
// x[b, a*85+ch, h, w] -> out[b, a*H*W + h*W + w, k], k in 0..83.
// R12: intra-block pipeline via inline asm (the compiler deleted it twice:
// R10 VGPR=32, R11 VGPR=28 -> loads sunk to use; and __syncthreads drains
// vmcnt(0) anyway). Per guide §5/T3/T4 + rule #18:
//  - volatile-asm global_load_dwordx4 (cannot be sunk/deleted)
//  - rB shares rA's address regs via offset:304 imm (tile1 = +76 floats)
//  - raw s_barrier with manual lgkmcnt(0) only -> prefetched loads stay
//    in flight ACROSS the barrier and overlap the drain's stores
//  - counted vmcnt(4)/vmcnt(3): in-order retirement makes the oldest
//    (loads) provably complete while stores may remain outstanding
//  - sched_barrier(0) after every waitcnt (hipcc hoists reg-only ops past
//    inline-asm waitcnt otherwise)
// NROWS=2, grid 48*38=1824 blocks x 512, LDS 85*77*4=26.2KB single-buffered.

#define YHW 5776
#define W76 76
#define NRB 38              // row-groups per plane = 76/2
#define LSTRIDE 77
#define NTHREADS 512
#define QN 19               // float4s per channel row (76 floats)
#define NQ (85 * QN)        // 1615
#define NJ 4                // ceil(1615/512)

typedef float f4v __attribute__((ext_vector_type(4)));

__device__ __forceinline__ float fsigmoid(float v) {
    return __builtin_amdgcn_rcpf(1.0f + __expf(-v));
}

__device__ __forceinline__ f4v aload0(const float* p) {
    f4v r;
    asm volatile("global_load_dwordx4 %0, %1, off" : "=v"(r) : "v"(p));
    return r;
}
__device__ __forceinline__ f4v aload304(const float* p) {   // +76 floats
    f4v r;
    asm volatile("global_load_dwordx4 %0, %1, off offset:304" : "=v"(r) : "v"(p));
    return r;
}

#define WAITCNT(s) do { asm volatile(s); __builtin_amdgcn_sched_barrier(0); } while (0)

__device__ __forceinline__ void transform(const f4v r[NJ], float (*lds)[LSTRIDE], int tid) {
    #pragma unroll
    for (int j = 0; j < NJ; ++j) {
        int idx = tid + NTHREADS * j;
        idx = (idx < NQ) ? idx : (NQ - 1);   // clamped lanes rewrite same value
        const int ch = idx / QN;
        const int q  = idx - ch * QN;
        f4v v = r[j];
        int row;
        if (ch < 2) {                   // tx,ty -> sigmoid*1.2-0.1
            v.x = fsigmoid(v.x) * 1.2f - 0.1f;
            v.y = fsigmoid(v.y) * 1.2f - 0.1f;
            v.z = fsigmoid(v.z) * 1.2f - 0.1f;
            v.w = fsigmoid(v.w) * 1.2f - 0.1f;
            row = ch;
        } else if (ch < 4) {            // tw,th -> exp
            v.x = __expf(v.x); v.y = __expf(v.y);
            v.z = __expf(v.z); v.w = __expf(v.w);
            row = ch;
        } else {                        // det + classes -> sigmoid
            v.x = fsigmoid(v.x); v.y = fsigmoid(v.y);
            v.z = fsigmoid(v.z); v.w = fsigmoid(v.w);
            row = (ch == 4) ? 84 : ch - 1;   // class ch -> row k (4..83)
        }
        const int p4 = 4 * q;
        lds[row][p4 + 0] = v.x;
        lds[row][p4 + 1] = v.y;
        lds[row][p4 + 2] = v.z;
        lds[row][p4 + 3] = v.w;
    }
}

__device__ __forceinline__ void drain(const float (*lds)[LSTRIDE], float* __restrict__ dst,
                                      int h, float ax, float ay, int tid) {
    const float inv = 1.0f / 76.0f;
    constexpr int total = W76 * 21;          // 1596
    #pragma unroll
    for (int u0 = 0; u0 < total; u0 += NTHREADS) {
        const int u = u0 + tid;
        if (u < total) {
            const int pp = u / 21;           // w coordinate directly
            const int c  = u - 21 * pp;
            f4v o;
            if (c == 0) {                    // box: rows 0..3, pure arithmetic
                const float sx = lds[0][pp];
                const float sy = lds[1][pp];
                const float ew = lds[2][pp];
                const float eh = lds[3][pp];
                const float bxc = (sx + (float)pp) * inv;
                const float byc = (sy + (float)h) * inv;
                const float bw  = ew * ax * inv;
                const float bh  = eh * ay * inv;
                const float bx1 = bxc - 0.5f * bw;
                const float by1 = byc - 0.5f * bh;
                o.x = bx1; o.y = by1; o.z = bx1 + bw; o.w = by1 + bh;
            } else {                         // classes k=4c..4c+3 at rows 4c..4c+3
                const float det = lds[84][pp];
                o.x = lds[4 * c + 0][pp] * det;
                o.y = lds[4 * c + 1][pp] * det;
                o.z = lds[4 * c + 2][pp] * det;
                o.w = lds[4 * c + 3][pp] * det;
            }
            *reinterpret_cast<f4v*>(dst + (size_t)pp * 84 + 4 * c) = o;
        }
    }
}

__global__ __launch_bounds__(NTHREADS) void yolo_kernel(const float* __restrict__ x,
                                                        float* __restrict__ out) {
    const int blk  = blockIdx.x;
    const int rb   = blk % NRB;
    const int ba   = blk / NRB;             // b*3 + a
    const int a    = ba % 3;
    const int row0 = rb * 2;

    __shared__ float lds[85][LSTRIDE];      // 26,180 B

    const int tid = threadIdx.x;
    const float* __restrict__ srcbase = x + (size_t)ba * 85 * YHW + (size_t)row0 * W76;
    float* __restrict__ dstbase = out + ((size_t)ba * YHW + (size_t)row0 * W76) * 84;

    const float ax = (a == 0) ? 1.5f : ((a == 1) ? 2.375f : 5.0f);
    const float ay = (a == 0) ? 2.0f : ((a == 1) ? 4.5f : 3.5f);

    // per-thread load addresses (shared by both tiles; tile1 = +304 B imm)
    const float* pj[NJ];
    #pragma unroll
    for (int j = 0; j < NJ; ++j) {
        int idx = tid + NTHREADS * j;
        idx = (idx < NQ) ? idx : (NQ - 1);
        const int ch = idx / QN;
        const int q  = idx - ch * QN;
        pj[j] = srcbase + (size_t)ch * YHW + 4 * q;
    }

    f4v rA[NJ], rB[NJ];
    #pragma unroll
    for (int j = 0; j < NJ; ++j) rA[j] = aload0(pj[j]);     // oldest 4
    #pragma unroll
    for (int j = 0; j < NJ; ++j) rB[j] = aload304(pj[j]);   // newest 4

    WAITCNT("s_waitcnt vmcnt(4)");          // rA ready; rB still in flight
    transform(rA, lds, tid);
    WAITCNT("s_waitcnt lgkmcnt(0)");        // LDS writes visible
    __builtin_amdgcn_s_barrier();           // NO vmcnt drain: rB stays in flight

    drain(lds, dstbase, row0, ax, ay, tid); // stores overlap rB loads

    WAITCNT("s_waitcnt lgkmcnt(0)");        // all my LDS reads done
    __builtin_amdgcn_s_barrier();
    WAITCNT("s_waitcnt vmcnt(3)");          // oldest 4 (rB) retired; stores may remain
    transform(rB, lds, tid);
    WAITCNT("s_waitcnt lgkmcnt(0)");
    __builtin_amdgcn_s_barrier();

    drain(lds, dstbase + (size_t)W76 * 84, row0 + 1, ax, ay, tid);
}

extern "C" void kernel_launch(void* const* d_in, const int* in_sizes, int n_in,
                              void* d_out, int out_size, void* d_ws, size_t ws_size,
                              hipStream_t stream) {
    const float* x = (const float*)d_in[0];
    float* out = (float*)d_out;
    const int nblocks = 48 * NRB;           // 16*3*38 = 1824
    yolo_kernel<<<nblocks, NTHREADS, 0, stream>>>(x, out);
}

// Round 6
// 35.235 us; speedup vs baseline: 1.0766x; 1.0389x over previous
//
#include <hip/hip_runtime.h>
#include <hip/hip_bf16.h>

// YOLOv4 head transform, B=16, A=3, nc=80, H=W=76.
// x[b, a*85+ch, h, w] -> out[b, a*H*W + h*W + w, k], k in 0..83.
// R13: exact R8 structure (best: 35.16us; PT=128, 512 thr, loads-first
// register staging, channel-major LDS stride 129, single barrier, float4
// drain) + NONTEMPORAL drain stores. Theory: the write-once output stream
// write-allocates in L2/L3 and evicts the not-yet-read input (FETCH 53.6MB
// < 94.3MB input shows partial L3 residency); nt stores keep the output out
// of the cache hierarchy, leaving L3 to the input. R12 falsified the
// latency-bubble theory (real asm pipeline = neutral), so the remaining
// ~20% gap to the mixed-stream floor is cache/DRAM stream structure.

#define YHW 5776
#define PT 128
#define NT 46              // 45 full 128-pos tiles + one 16-pos tail per plane
#define LSTRIDE 129        // odd stride: build writes ~2-way (free)
#define NTHREADS 512

typedef float f4v __attribute__((ext_vector_type(4)));

__device__ __forceinline__ float fsigmoid(float v) {
    return __builtin_amdgcn_rcpf(1.0f + __expf(-v));
}

// QL = log2(float4s per channel row): 5 (npos=128) or 2 (npos=16)
template<int QL>
__device__ __forceinline__ void build(const float* __restrict__ src,
                                      float (*lds)[LSTRIDE], int tid) {
    constexpr int NQ = 85 << QL;                    // 2720 / 340
    constexpr int NJ = (NQ + NTHREADS - 1) / NTHREADS;  // 6 / 1
    f4v r[NJ];
    #pragma unroll
    for (int j = 0; j < NJ; ++j) {                  // ALL loads issued before any use
        const int idx = tid + NTHREADS * j;
        if (idx < NQ) {
            const int ch = idx >> QL;
            const int q  = idx & ((1 << QL) - 1);
            r[j] = *reinterpret_cast<const f4v*>(src + (size_t)ch * YHW + 4 * q);
        }
    }
    #pragma unroll
    for (int j = 0; j < NJ; ++j) {
        const int idx = tid + NTHREADS * j;
        if (idx < NQ) {
            const int ch = idx >> QL;
            const int q  = idx & ((1 << QL) - 1);
            f4v v = r[j];
            int row;
            if (ch < 2) {                   // tx,ty -> sigmoid*1.2-0.1
                v.x = fsigmoid(v.x) * 1.2f - 0.1f;
                v.y = fsigmoid(v.y) * 1.2f - 0.1f;
                v.z = fsigmoid(v.z) * 1.2f - 0.1f;
                v.w = fsigmoid(v.w) * 1.2f - 0.1f;
                row = ch;
            } else if (ch < 4) {            // tw,th -> exp
                v.x = __expf(v.x); v.y = __expf(v.y);
                v.z = __expf(v.z); v.w = __expf(v.w);
                row = ch;
            } else {                        // det + classes -> sigmoid
                v.x = fsigmoid(v.x); v.y = fsigmoid(v.y);
                v.z = fsigmoid(v.z); v.w = fsigmoid(v.w);
                row = (ch == 4) ? 84 : ch - 1;   // class ch -> row k (4..83)
            }
            const int p4 = 4 * q;
            lds[row][p4 + 0] = v.x;
            lds[row][p4 + 1] = v.y;
            lds[row][p4 + 2] = v.z;
            lds[row][p4 + 3] = v.w;
        }
    }
}

__global__ __launch_bounds__(NTHREADS) void yolo_kernel(const float* __restrict__ x,
                                                        float* __restrict__ out) {
    const int blk  = blockIdx.x;
    const int tile = blk % NT;
    const int ba   = blk / NT;              // b*3 + a
    const int a    = ba % 3;
    const int p0   = tile * PT;
    const int npos = (tile == NT - 1) ? 16 : PT;

    __shared__ float lds[85][LSTRIDE];      // 43,860 B -> 3 blocks/CU

    const float* __restrict__ src = x + (size_t)ba * 85 * YHW + p0;
    const int tid = threadIdx.x;

    if (npos == PT) build<5>(src, lds, tid);
    else            build<2>(src, lds, tid);
    __syncthreads();                        // the only barrier

    const float ax  = (a == 0) ? 1.5f : ((a == 1) ? 2.375f : 5.0f);
    const float ay  = (a == 0) ? 2.0f : ((a == 1) ? 4.5f : 3.5f);
    const float inv = 1.0f / 76.0f;
    float* __restrict__ dst = out + ((size_t)ba * YHW + p0) * 84;

    const int total = npos * 21;            // 2688 / 336
    for (int u = tid; u < total; u += NTHREADS) {
        const int pp = u / 21;
        const int c  = u - 21 * pp;
        f4v o;
        if (c == 0) {                       // box: rows 0..3, pure arithmetic
            const float sx = lds[0][pp];
            const float sy = lds[1][pp];
            const float ew = lds[2][pp];
            const float eh = lds[3][pp];
            const int p = p0 + pp;
            const int h = p / 76;
            const int w = p - 76 * h;
            const float bxc = (sx + (float)w) * inv;
            const float byc = (sy + (float)h) * inv;
            const float bw  = ew * ax * inv;
            const float bh  = eh * ay * inv;
            const float bx1 = bxc - 0.5f * bw;
            const float by1 = byc - 0.5f * bh;
            o.x = bx1; o.y = by1; o.z = bx1 + bw; o.w = by1 + bh;
        } else {                            // classes k=4c..4c+3 at rows 4c..4c+3
            const float det = lds[84][pp];
            o.x = lds[4 * c + 0][pp] * det;
            o.y = lds[4 * c + 1][pp] * det;
            o.z = lds[4 * c + 2][pp] * det;
            o.w = lds[4 * c + 3][pp] * det;
        }
        // Nontemporal: output is write-once, never re-read -> don't let it
        // evict the input from L2/L3.
        __builtin_nontemporal_store(o, reinterpret_cast<f4v*>(dst + (size_t)pp * 84 + 4 * c));
    }
}

extern "C" void kernel_launch(void* const* d_in, const int* in_sizes, int n_in,
                              void* d_out, int out_size, void* d_ws, size_t ws_size,
                              hipStream_t stream) {
    const float* x = (const float*)d_in[0];
    float* out = (float*)d_out;
    const int nblocks = 48 * NT;            // 16*3*46 = 2208
    yolo_kernel<<<nblocks, NTHREADS, 0, stream>>>(x, out);
}

// Round 7
// 35.229 us; speedup vs baseline: 1.0767x; 1.0002x over previous
//
#include <hip/hip_runtime.h>

// YOLOv4 head transform, B=16, A=3, nc=80, H=W=76.
// x[b, a*85+ch, h, w] -> out[b, a*H*W + h*W + w, k], k in 0..83.
// R14: R8's proven shell (PT=128, 512 thr, 2208 blocks, loads-first reg
// staging, single barrier) with POSITION-MAJOR LDS: lds[pos][slot], LS=96.
// Drain reads each output float4 as ONE ds_read_b128 (slots 4c..4c+3; box
// slots 0..3 = sx,sy,ew,eh) + broadcast det read, replacing 5 scalar
// ds_read_b32 (3.59M measured conflict cycles + 5x address math). Build's
// column writes (stride 96 floats = same-bank) are de-conflicted by an XOR
// swizzle on slot bits 2..4: slot' = slot ^ ((q&7)<<2)  (pos>>2 == q), max
// swizzled slot 95 < 96. LDS 128*96*4 = 48KB -> 3 blocks/CU (same as R8).

#define YHW 5776
#define PT 128
#define NT 46              // 45 full 128-pos tiles + one 16-pos tail per plane
#define LS 96              // row stride (floats); mult of 4 for b128 alignment
#define NTHREADS 512

typedef float f4v __attribute__((ext_vector_type(4)));

__device__ __forceinline__ float fsigmoid(float v) {
    return __builtin_amdgcn_rcpf(1.0f + __expf(-v));
}

// QL = log2(float4s per channel row): 5 (npos=128) or 2 (npos=16)
template<int QL>
__device__ __forceinline__ void build(const float* __restrict__ src,
                                      float* lds, int tid) {
    constexpr int NQ = 85 << QL;                        // 2720 / 340
    constexpr int NJ = (NQ + NTHREADS - 1) / NTHREADS;  // 6 / 1
    f4v r[NJ];
    #pragma unroll
    for (int j = 0; j < NJ; ++j) {                  // ALL loads issued before any use
        const int idx = tid + NTHREADS * j;
        if (idx < NQ) {
            const int ch = idx >> QL;
            const int q  = idx & ((1 << QL) - 1);
            r[j] = *reinterpret_cast<const f4v*>(src + (size_t)ch * YHW + 4 * q);
        }
    }
    #pragma unroll
    for (int j = 0; j < NJ; ++j) {
        const int idx = tid + NTHREADS * j;
        if (idx < NQ) {
            const int ch = idx >> QL;
            const int q  = idx & ((1 << QL) - 1);
            f4v v = r[j];
            int slot;
            if (ch < 2) {                   // tx,ty -> sigmoid*1.2-0.1
                v.x = fsigmoid(v.x) * 1.2f - 0.1f;
                v.y = fsigmoid(v.y) * 1.2f - 0.1f;
                v.z = fsigmoid(v.z) * 1.2f - 0.1f;
                v.w = fsigmoid(v.w) * 1.2f - 0.1f;
                slot = ch;
            } else if (ch < 4) {            // tw,th -> exp
                v.x = __expf(v.x); v.y = __expf(v.y);
                v.z = __expf(v.z); v.w = __expf(v.w);
                slot = ch;
            } else {                        // det + classes -> sigmoid
                v.x = fsigmoid(v.x); v.y = fsigmoid(v.y);
                v.z = fsigmoid(v.z); v.w = fsigmoid(v.w);
                slot = (ch == 4) ? 84 : ch - 1;   // class ch -> slot k (4..83)
            }
            // 4 positions (4q..4q+3) of one slot; swizzle slot bits 2..4 by
            // pos>>2 (== q) to spread the stride-96 column writes over banks.
            const int slotp = slot ^ ((q & 7) << 2);
            float* p = lds + (size_t)(4 * q) * LS + slotp;
            p[0 * LS] = v.x;
            p[1 * LS] = v.y;
            p[2 * LS] = v.z;
            p[3 * LS] = v.w;
        }
    }
}

__global__ __launch_bounds__(NTHREADS) void yolo_kernel(const float* __restrict__ x,
                                                        float* __restrict__ out) {
    const int blk  = blockIdx.x;
    const int tile = blk % NT;
    const int ba   = blk / NT;              // b*3 + a
    const int a    = ba % 3;
    const int p0   = tile * PT;
    const int npos = (tile == NT - 1) ? 16 : PT;

    __shared__ float lds[PT * LS];          // 49,152 B -> 3 blocks/CU

    const float* __restrict__ src = x + (size_t)ba * 85 * YHW + p0;
    const int tid = threadIdx.x;

    if (npos == PT) build<5>(src, lds, tid);
    else            build<2>(src, lds, tid);
    __syncthreads();                        // the only barrier

    const float ax  = (a == 0) ? 1.5f : ((a == 1) ? 2.375f : 5.0f);
    const float ay  = (a == 0) ? 2.0f : ((a == 1) ? 4.5f : 3.5f);
    const float inv = 1.0f / 76.0f;
    float* __restrict__ dst = out + ((size_t)ba * YHW + p0) * 84;

    const int total = npos * 21;            // 2688 / 336
    for (int u = tid; u < total; u += NTHREADS) {
        const int pp = u / 21;
        const int c  = u - 21 * pp;
        const int sw = ((pp >> 2) & 7) << 2;            // same swizzle as build
        const float* row = lds + (size_t)pp * LS;
        const f4v o4 = *reinterpret_cast<const f4v*>(row + ((4 * c) ^ sw));
        f4v o;
        if (c == 0) {                       // o4 = sx, sy, ew, eh
            const int p = p0 + pp;
            const int h = p / 76;
            const int w = p - 76 * h;
            const float bxc = (o4.x + (float)w) * inv;
            const float byc = (o4.y + (float)h) * inv;
            const float bw  = o4.z * ax * inv;
            const float bh  = o4.w * ay * inv;
            const float bx1 = bxc - 0.5f * bw;
            const float by1 = byc - 0.5f * bh;
            o.x = bx1; o.y = by1; o.z = bx1 + bw; o.w = by1 + bh;
        } else {                            // classes k=4c..4c+3, scaled by det
            const float det = row[84 ^ sw]; // broadcast within same-pp lanes
            o.x = o4.x * det;
            o.y = o4.y * det;
            o.z = o4.z * det;
            o.w = o4.w * det;
        }
        *reinterpret_cast<f4v*>(dst + (size_t)pp * 84 + 4 * c) = o;
    }
}

extern "C" void kernel_launch(void* const* d_in, const int* in_sizes, int n_in,
                              void* d_out, int out_size, void* d_ws, size_t ws_size,
                              hipStream_t stream) {
    const float* x = (const float*)d_in[0];
    float* out = (float*)d_out;
    const int nblocks = 48 * NT;            // 16*3*46 = 2208
    yolo_kernel<<<nblocks, NTHREADS, 0, stream>>>(x, out);
}